// Round 18
// baseline (29.849 us; speedup 1.0000x reference)
//
#include <hip/hip_runtime.h>
#include <hip/hip_bf16.h>

#define IN_F   4096
#define OUT_F  11008
#define BATCH  32
#define NTILE  16
#define KSPLIT 2
#define GRID_N (OUT_F / NTILE)    // 688
#define OUTSZ  (BATCH * OUT_F)

typedef __attribute__((ext_vector_type(8))) short  bf16x8;
typedef __attribute__((ext_vector_type(4))) float  f32x4;
typedef __attribute__((ext_vector_type(4))) int    i32x4;
typedef __attribute__((ext_vector_type(4))) float  float4v;

static __device__ __constant__ float NF4_LEVELS[16] = {
    -1.0f, -0.6961928009986877f, -0.5250730514526367f, -0.39491748809814453f,
    -0.28444138169288635f, -0.18477343022823334f, -0.09105003625154495f, 0.0f,
    0.07958029955625534f, 0.16093020141124725f, 0.24611230194568634f,
    0.33791524171829224f, 0.44070982933044434f, 0.5626170039176941f,
    0.7229568362236023f, 1.0f};

// ---------------------------------------------------------------------------
// Prelude (408 blocks):
//   bid <  64: A-fragment streams in MFMA order:
//     frag[st][kb][lane] (16B) = x[st*16+(lane&15)][kb*32+(lane>>4)*8..+8) bf16
//   bid >= 64: out[b][o] = bias[o]  (base for gemm atomics)
// ---------------------------------------------------------------------------
__global__ void prelude_kernel(const float* __restrict__ x,
                               const float* __restrict__ bias,
                               unsigned short* __restrict__ frag,
                               float* __restrict__ out) {
    const int bid = blockIdx.x, tid = threadIdx.x;
    if (bid < 64) {
        int T  = bid * 256 + tid;
        int st = T >> 13;
        int kb = (T >> 6) & 127;
        int l  = T & 63;
        int row = st * 16 + (l & 15);
        int k0  = kb * 32 + (l >> 4) * 8;
        const float* src = x + (size_t)row * IN_F + k0;
        unsigned w[4];
        #pragma unroll
        for (int e = 0; e < 4; ++e) {
            unsigned lo = __builtin_bit_cast(unsigned short, __float2bfloat16(src[2 * e]));
            unsigned hi = __builtin_bit_cast(unsigned short, __float2bfloat16(src[2 * e + 1]));
            w[e] = lo | (hi << 16);
        }
        i32x4 v = { (int)w[0], (int)w[1], (int)w[2], (int)w[3] };
        *reinterpret_cast<i32x4*>(frag + ((size_t)st * 8192 + kb * 64 + l) * 8) = v;
    } else {
        int t2 = (bid - 64) * 256 + tid;     // [0, 88064)
        int i  = t2 * 4;
        int o  = i % OUT_F;
        float4v b = *reinterpret_cast<const float4v*>(bias + o);
        *reinterpret_cast<float4v*>(out + i) = b;
    }
}

// ---------------------------------------------------------------------------
// Main: the R10-measured kernel (19.3us/pass in 3-replica throughput regime),
// made single-GEMM multi-round: grid (688, 2) = 1376 blocks (>1 residency
// round at 4 blocks/CU -> block-level pipelining by the HW scheduler).
// Block = 16 out-rows x 2048 k as 4 units of 512 k, stage-ahead-2:
//   iter u: issue loads(u+2) -> compute(u) from buf[u&1] -> write(u+1) -> bar.
// Waves split each unit's K 4-ways (wave w owns group u*4+w of the unit).
// Staging per unit: wave w stages rows w*4..+3; one row-chunk = 256 int32 =
//   one contiguous 1KB wave-load; compact 4 int32 -> code dword (j=lane).
//   Store (row*64 + p(j)) ^ ((row&7)<<2), p(j)=(j&0x30)|((j&3)<<2)|((j>>2)&3).
//   Reader: ds_read_b128 at (col*64 + w*16 + g*4) ^ ((col&7)<<2) = ksteps 0..3.
// Epilogue: cross-wave K-reduce in aliased LDS + 2-writer unsafeAtomicAdd
// into bias-initialized out.
// ---------------------------------------------------------------------------
__global__ __launch_bounds__(256, 4) void nf4_gemm_kernel(
        const int* __restrict__ packed,
        const float* __restrict__ scales,
        const unsigned short* __restrict__ frag,
        float* __restrict__ out)
{
    __shared__ unsigned tabu[256];
    __shared__ float    slds[512];       // scales[32 groups][16 rows]
    __shared__ unsigned buf[2][1024];    // 2 x 4KB code dwords; red alias

    const int tid  = threadIdx.x;
    const int wave = tid >> 6;
    const int lane = tid & 63;
    const int col  = lane & 15;
    const int g    = lane >> 4;

    {
        unsigned lo = __builtin_bit_cast(unsigned short, __float2bfloat16(NF4_LEVELS[tid & 15]));
        unsigned hi = __builtin_bit_cast(unsigned short, __float2bfloat16(NF4_LEVELS[(tid >> 4) & 15]));
        tabu[tid] = lo | (hi << 16);
    }

    const int n0 = blockIdx.x * NTILE;
    const int by = blockIdx.y;           // k-half 0/1

    // stage scales for this block's 16 rows (all 32 groups, 2KB contiguous)
    {
        int e = tid * 2;
        float2 sv = *reinterpret_cast<const float2*>(scales + (size_t)n0 * 32 + e);
        int c0 = e >> 5, g0 = e & 31;
        slds[g0 * 16 + c0]       = sv.x;
        slds[(g0 + 1) * 16 + c0] = sv.y;
    }

    const int dperm = (lane & 0x30) | ((lane & 3) << 2) | ((lane >> 2) & 3);

    #define PLOAD(u, sr)                                                       \
        _Pragma("unroll")                                                      \
        for (int ii = 0; ii < 4; ++ii) {                                       \
            sr[ii] = *reinterpret_cast<const i32x4*>(                          \
                packed + (size_t)(n0 + wave * 4 + ii) * (IN_F / 2)             \
                       + by * 1024 + (u) * 256 + lane * 4);                    \
        }

    #define PWRITE(u, sr)                                                      \
        _Pragma("unroll")                                                      \
        for (int ii = 0; ii < 4; ++ii) {                                       \
            int row = wave * 4 + ii;                                           \
            unsigned v = ((unsigned)(sr[ii][0] & 255))                         \
                       | ((unsigned)(sr[ii][1] & 255) << 8)                    \
                       | ((unsigned)(sr[ii][2] & 255) << 16)                   \
                       | ((unsigned)(sr[ii][3] & 255) << 24);                  \
            buf[(u) & 1][(row * 64 + dperm) ^ ((row & 7) << 2)] = v;           \
        }

    // prologue: loads for units 0 and 1 in flight; write unit 0
    i32x4 sB[4];
    {
        i32x4 sA[4];
        PLOAD(0, sA)
        PLOAD(1, sB)
        PWRITE(0, sA)
    }
    __syncthreads();

    f32x4 acc0 = (f32x4){0.f,0.f,0.f,0.f};   // batch 0-15
    f32x4 acc1 = (f32x4){0.f,0.f,0.f,0.f};   // batch 16-31

    const unsigned short* f0 = frag;
    const unsigned short* f1 = frag + 65536;

    #pragma unroll
    for (int u = 0; u < 4; ++u) {
        i32x4 sC[4];
        if (u + 2 < 4) { PLOAD(u + 2, sC) }      // sustained lookahead-2

        // A fragments for this unit (8 x 1KB contiguous, L2-resident)
        bf16x8 A0[4], A1[4];
        #pragma unroll
        for (int t = 0; t < 4; ++t) {
            int kb = by * 64 + u * 16 + wave * 4 + t;
            A0[t] = *reinterpret_cast<const bf16x8*>(f0 + ((size_t)kb * 64 + lane) * 8);
            A1[t] = *reinterpret_cast<const bf16x8*>(f1 + ((size_t)kb * 64 + lane) * 8);
        }

        i32x4 cdv = *reinterpret_cast<const i32x4*>(
            &buf[u & 1][(col * 64 + wave * 16 + g * 4) ^ ((col & 7) << 2)]);
        float sc = slds[(by * 16 + u * 4 + wave) * 16 + col];

        f32x4 t0 = (f32x4){0.f,0.f,0.f,0.f};
        f32x4 t1 = (f32x4){0.f,0.f,0.f,0.f};
        #pragma unroll
        for (int t = 0; t < 4; ++t) {
            unsigned code = (unsigned)cdv[t];
            i32x4 bu;                            // bfrag once, both halves
            bu[0] = (int)tabu[code & 255u];
            bu[1] = (int)tabu[(code >> 8) & 255u];
            bu[2] = (int)tabu[(code >> 16) & 255u];
            bu[3] = (int)tabu[code >> 24];
            bf16x8 bf = __builtin_bit_cast(bf16x8, bu);
            t0 = __builtin_amdgcn_mfma_f32_16x16x32_bf16(A0[t], bf, t0, 0, 0, 0);
            t1 = __builtin_amdgcn_mfma_f32_16x16x32_bf16(A1[t], bf, t1, 0, 0, 0);
        }
        #pragma unroll
        for (int j = 0; j < 4; ++j) {
            acc0[j] = fmaf(sc, t0[j], acc0[j]);
            acc1[j] = fmaf(sc, t1[j], acc1[j]);
        }

        if (u + 1 < 4) { PWRITE(u + 1, sB) }     // into buf[!(u&1)], safe
        #pragma unroll
        for (int ii = 0; ii < 4; ++ii) sB[ii] = sC[ii];

        __syncthreads();
    }

    // ---- cross-wave K-reduce in aliased LDS, atomic accumulate ----
    float* red = (float*)buf;
    #pragma unroll
    for (int j = 0; j < 4; ++j) {
        red[wave * 512 + j * 64 + lane]       = acc0[j];
        red[wave * 512 + (4 + j) * 64 + lane] = acc1[j];
    }
    __syncthreads();

    #pragma unroll
    for (int p = 0; p < 2; ++p) {
        int idx = p * 256 + tid;             // [0,512): b = idx>>4, c = idx&15
        int b   = idx >> 4;
        int c   = idx & 15;
        int h   = b >> 4;
        int r4  = b & 15;
        int j   = r4 & 3;
        int lg  = r4 >> 2;
        int slot = (h * 4 + j) * 64 + lg * 16 + c;
        float s = red[slot] + red[512 + slot] + red[1024 + slot] + red[1536 + slot];
        unsafeAtomicAdd(out + (size_t)b * OUT_F + n0 + c, s);
    }
}

// ---------------------------------------------------------------------------
extern "C" void kernel_launch(void* const* d_in, const int* in_sizes, int n_in,
                              void* d_out, int out_size, void* d_ws, size_t ws_size,
                              hipStream_t stream) {
    const float* x      = (const float*)d_in[0];
    const int*   packed = (const int*)d_in[1];
    const float* scales = (const float*)d_in[2];
    const float* bias   = (const float*)d_in[3];
    float* out = (float*)d_out;

    unsigned short* frag = (unsigned short*)d_ws;   // 256 KB

    prelude_kernel<<<408, 256, 0, stream>>>(x, bias, frag, out);
    nf4_gemm_kernel<<<dim3(GRID_N, KSPLIT), 256, 0, stream>>>(packed, scales, frag, out);
}

// Round 19
// 28.008 us; speedup vs baseline: 1.0658x; 1.0658x over previous
//
#include <hip/hip_runtime.h>
#include <hip/hip_bf16.h>

#define IN_F   4096
#define OUT_F  11008
#define BATCH  32
#define NTILE  16
#define GRID_N (OUT_F / NTILE)    // 688

typedef __attribute__((ext_vector_type(8))) short  bf16x8;
typedef __attribute__((ext_vector_type(4))) float  f32x4;
typedef __attribute__((ext_vector_type(4))) int    i32x4;
typedef __attribute__((ext_vector_type(4))) float  float4v;

static __device__ __constant__ float NF4_LEVELS[16] = {
    -1.0f, -0.6961928009986877f, -0.5250730514526367f, -0.39491748809814453f,
    -0.28444138169288635f, -0.18477343022823334f, -0.09105003625154495f, 0.0f,
    0.07958029955625534f, 0.16093020141124725f, 0.24611230194568634f,
    0.33791524171829224f, 0.44070982933044434f, 0.5626170039176941f,
    0.7229568362236023f, 1.0f};

// ---------------------------------------------------------------------------
// Prelude (64 blocks): A-fragment streams in MFMA order:
//   frag[st][kb][lane] (16B) = x[st*16+(lane&15)][kb*32+(lane>>4)*8..+8) bf16
// ---------------------------------------------------------------------------
__global__ void prelude_kernel(const float* __restrict__ x,
                               unsigned short* __restrict__ frag) {
    int T  = blockIdx.x * 256 + threadIdx.x;
    int st = T >> 13;
    int kb = (T >> 6) & 127;
    int l  = T & 63;
    int row = st * 16 + (l & 15);
    int k0  = kb * 32 + (l >> 4) * 8;
    const float* src = x + (size_t)row * IN_F + k0;
    unsigned w[4];
    #pragma unroll
    for (int e = 0; e < 4; ++e) {
        unsigned lo = __builtin_bit_cast(unsigned short, __float2bfloat16(src[2 * e]));
        unsigned hi = __builtin_bit_cast(unsigned short, __float2bfloat16(src[2 * e + 1]));
        w[e] = lo | (hi << 16);
    }
    i32x4 v = { (int)w[0], (int)w[1], (int)w[2], (int)w[3] };
    *reinterpret_cast<i32x4*>(frag + ((size_t)st * 8192 + kb * 64 + l) * 8) = v;
}

// ---------------------------------------------------------------------------
// Main: grid 688, 256 thr (4 waves), BARRIER-FREE K-loop. [R13 — best
// measured of 19 rounds: 28.0us. Reverted verbatim after 9 falsified
// alternative theories; see session journal R14-R18.]
// Block = 16 out-rows x full K=4096; wave w owns k [w*1024,+1024) as 2 units
// of 512 k. Everything a wave needs is wave-private:
//   - tabu copy      lds[wave*256 + e]                    (1KB/wave)
//   - code buffers   lds[1024 + (wave*2+u)*1024 + ...]    (2 x 4KB/wave)
//   - scales         scw[8] in registers
// => no __syncthreads until the single cross-wave reduce at the end; the
// compiler's vmcnt(0)-before-barrier drain (the structural stall of R5-R12)
// is gone: unit-1 loads issue during unit-0 compute and stay in flight.
//
// Staging: per unit, 16 rows; one row = 256 consecutive int32 = one 1KB
//   wave-load; compact 4 int32 -> 1 code dword (lane j covers unit-k [8j,8j+8)).
//   Store at (row*64 + p(j)) ^ ((row&7)<<2), p(j)=(j&0x30)|((j&3)<<2)|((j>>2)&3)
//   -> reader ds_read_b128 at (col*64 + grp*16 + g*4) ^ ((col&7)<<2) yields
//   k-steps t=0..3 of group grp. Writes 2 lanes/bank, reads ~2-way (free).
// Epilogue: one barrier, cross-wave (K) sum from aliased red regions, + bias,
// direct store. No atomics anywhere.
// ---------------------------------------------------------------------------
__global__ __launch_bounds__(256, 3) void nf4_gemm_kernel(
        const int* __restrict__ packed,
        const float* __restrict__ scales,
        const float* __restrict__ bias,
        const unsigned short* __restrict__ frag,
        float* __restrict__ out)
{
    __shared__ unsigned lds[9216];   // 36KB: 4x256 tabu | 8x1024 code dwords

    const int tid  = threadIdx.x;
    const int wave = tid >> 6;
    const int lane = tid & 63;
    const int col  = lane & 15;
    const int g    = lane >> 4;

    const int n0 = blockIdx.x * NTILE;

    // ---- wave-private tabu (no barrier needed) ----
    #pragma unroll
    for (int q = 0; q < 4; ++q) {
        int e = q * 64 + lane;
        unsigned lo = __builtin_bit_cast(unsigned short, __float2bfloat16(NF4_LEVELS[e & 15]));
        unsigned hi = __builtin_bit_cast(unsigned short, __float2bfloat16(NF4_LEVELS[(e >> 4) & 15]));
        lds[wave * 256 + e] = lo | (hi << 16);
    }

    // ---- scales in registers: this lane's row = n0+col, groups wave*8..+8 ----
    float scw[8];
    {
        const float* sp = scales + (size_t)(n0 + col) * 32 + wave * 8;
        float4v sv0 = *reinterpret_cast<const float4v*>(sp);
        float4v sv1 = *reinterpret_cast<const float4v*>(sp + 4);
        scw[0]=sv0.x; scw[1]=sv0.y; scw[2]=sv0.z; scw[3]=sv0.w;
        scw[4]=sv1.x; scw[5]=sv1.y; scw[6]=sv1.z; scw[7]=sv1.w;
    }

    const int dperm = (lane & 0x30) | ((lane & 3) << 2) | ((lane >> 2) & 3);

    // batch = 8 rows (r0 = 0 or 8) of unit u; one contiguous 1KB load per row
    #define PLOAD(u, r0, sr)                                                   \
        _Pragma("unroll")                                                      \
        for (int ii = 0; ii < 8; ++ii) {                                       \
            sr[ii] = *reinterpret_cast<const i32x4*>(                          \
                packed + (size_t)(n0 + (r0) + ii) * (IN_F / 2)                 \
                       + wave * 512 + (u) * 256 + lane * 4);                   \
        }

    #define PWRITE(u, r0, sr)                                                  \
        _Pragma("unroll")                                                      \
        for (int ii = 0; ii < 8; ++ii) {                                       \
            int row = (r0) + ii;                                               \
            unsigned v = ((unsigned)(sr[ii][0] & 255))                         \
                       | ((unsigned)(sr[ii][1] & 255) << 8)                    \
                       | ((unsigned)(sr[ii][2] & 255) << 16)                   \
                       | ((unsigned)(sr[ii][3] & 255) << 24);                  \
            lds[1024 + (wave * 2 + (u)) * 1024                                 \
                + ((row * 64 + dperm) ^ ((row & 7) << 2))] = v;                \
        }

    f32x4 acc0 = (f32x4){0.f,0.f,0.f,0.f};   // batch 0-15
    f32x4 acc1 = (f32x4){0.f,0.f,0.f,0.f};   // batch 16-31

    const unsigned short* f0 = frag;
    const unsigned short* f1 = frag + 65536;

    // one group = 128 k of unit u: 1 b128 code read + 8 A-loads + 8 MFMA
    #define COMPUTE_GRP(u, grp)                                                \
    {                                                                          \
        i32x4 cd = *reinterpret_cast<const i32x4*>(                            \
            &lds[1024 + (wave * 2 + (u)) * 1024                                \
                 + ((col * 64 + (grp) * 16 + g * 4) ^ ((col & 7) << 2))]);     \
        bf16x8 A0[4], A1[4];                                                   \
        _Pragma("unroll")                                                      \
        for (int t = 0; t < 4; ++t) {                                          \
            int kb = wave * 32 + (u) * 16 + (grp) * 4 + t;                     \
            A0[t] = *reinterpret_cast<const bf16x8*>(f0 + ((size_t)kb * 64 + lane) * 8); \
            A1[t] = *reinterpret_cast<const bf16x8*>(f1 + ((size_t)kb * 64 + lane) * 8); \
        }                                                                      \
        f32x4 t0 = (f32x4){0.f,0.f,0.f,0.f};                                   \
        f32x4 t1 = (f32x4){0.f,0.f,0.f,0.f};                                   \
        _Pragma("unroll")                                                      \
        for (int t = 0; t < 4; ++t) {                                          \
            unsigned code = (unsigned)cd[t];                                   \
            i32x4 bu;                                                          \
            bu[0] = (int)lds[wave * 256 + (code & 255u)];                      \
            bu[1] = (int)lds[wave * 256 + ((code >> 8) & 255u)];               \
            bu[2] = (int)lds[wave * 256 + ((code >> 16) & 255u)];              \
            bu[3] = (int)lds[wave * 256 + (code >> 24)];                       \
            bf16x8 bf = __builtin_bit_cast(bf16x8, bu);                        \
            t0 = __builtin_amdgcn_mfma_f32_16x16x32_bf16(A0[t], bf, t0, 0, 0, 0); \
            t1 = __builtin_amdgcn_mfma_f32_16x16x32_bf16(A1[t], bf, t1, 0, 0, 0); \
        }                                                                      \
        const float sc = scw[(u) * 4 + (grp)];                                 \
        _Pragma("unroll")                                                      \
        for (int j = 0; j < 4; ++j) {                                          \
            acc0[j] = fmaf(sc, t0[j], acc0[j]);                                \
            acc1[j] = fmaf(sc, t1[j], acc1[j]);                                \
        }                                                                      \
    }

    // ---- barrier-free pipeline ----
    i32x4 sa[8], sb[8];
    PLOAD(0, 0, sa)
    PLOAD(0, 8, sb)
    PWRITE(0, 0, sa)             // waits only its own vmcnt (sb stays in flight)
    PWRITE(0, 8, sb)

    COMPUTE_GRP(0, 0)
    PLOAD(1, 0, sa)              // unit-1 loads fly under unit-0 compute
    COMPUTE_GRP(0, 1)
    PLOAD(1, 8, sb)
    COMPUTE_GRP(0, 2)
    COMPUTE_GRP(0, 3)

    PWRITE(1, 0, sa)
    PWRITE(1, 8, sb)
    COMPUTE_GRP(1, 0)
    COMPUTE_GRP(1, 1)
    COMPUTE_GRP(1, 2)
    COMPUTE_GRP(1, 3)

    // ---- epilogue: red aliases wave's unit-0 code buffer (own reads done) ----
    float* red = (float*)&lds[1024 + wave * 2048];
    #pragma unroll
    for (int j = 0; j < 4; ++j) {
        red[(0 * 4 + j) * 64 + g * 16 + col] = acc0[j];
        red[(1 * 4 + j) * 64 + g * 16 + col] = acc1[j];
    }
    __syncthreads();             // the ONE barrier

    #pragma unroll
    for (int p = 0; p < 2; ++p) {
        int idx = p * 256 + tid;             // [0,512)
        int b   = idx >> 4;                  // batch row
        int c   = idx & 15;                  // out-feature local
        int h   = b >> 4;
        int r   = b & 15;
        int j   = r & 3;
        int g2  = r >> 2;
        int slot = (h * 4 + j) * 64 + g2 * 16 + c;
        const float* rbase = (const float*)&lds[1024];
        float s = rbase[slot] + rbase[2048 / 4 * 4 + slot]   // wave1: +2048 dwords
                + rbase[4096 + slot] + rbase[6144 + slot];
        out[(size_t)b * OUT_F + n0 + c] = s + bias[n0 + c];
    }
}

// ---------------------------------------------------------------------------
extern "C" void kernel_launch(void* const* d_in, const int* in_sizes, int n_in,
                              void* d_out, int out_size, void* d_ws, size_t ws_size,
                              hipStream_t stream) {
    const float* x      = (const float*)d_in[0];
    const int*   packed = (const int*)d_in[1];
    const float* scales = (const float*)d_in[2];
    const float* bias   = (const float*)d_in[3];
    float* out = (float*)d_out;

    unsigned short* frag = (unsigned short*)d_ws;   // 256 KB

    prelude_kernel<<<64, 256, 0, stream>>>(x, frag);
    nf4_gemm_kernel<<<GRID_N, 256, 0, stream>>>(packed, scales, bias, frag, out);
}

// Round 20
// 26.196 us; speedup vs baseline: 1.1395x; 1.0692x over previous
//
#include <hip/hip_runtime.h>
#include <hip/hip_bf16.h>

#define IN_F   4096
#define OUT_F  11008
#define BATCH  32
#define NTILE  16
#define GRID_N (OUT_F / NTILE)    // 688

typedef __attribute__((ext_vector_type(8))) short  bf16x8;
typedef __attribute__((ext_vector_type(4))) float  f32x4;
typedef __attribute__((ext_vector_type(4))) int    i32x4;
typedef __attribute__((ext_vector_type(4))) float  float4v;

static __device__ __constant__ float NF4_LEVELS[16] = {
    -1.0f, -0.6961928009986877f, -0.5250730514526367f, -0.39491748809814453f,
    -0.28444138169288635f, -0.18477343022823334f, -0.09105003625154495f, 0.0f,
    0.07958029955625534f, 0.16093020141124725f, 0.24611230194568634f,
    0.33791524171829224f, 0.44070982933044434f, 0.5626170039176941f,
    0.7229568362236023f, 1.0f};

// ---------------------------------------------------------------------------
// Prelude (64 blocks): A-fragment streams in MFMA order:
//   frag[st][kb][lane] (16B) = x[st*16+(lane&15)][kb*32+(lane>>4)*8..+8) bf16
// ---------------------------------------------------------------------------
__global__ void prelude_kernel(const float* __restrict__ x,
                               unsigned short* __restrict__ frag) {
    int T  = blockIdx.x * 256 + threadIdx.x;
    int st = T >> 13;
    int kb = (T >> 6) & 127;
    int l  = T & 63;
    int row = st * 16 + (l & 15);
    int k0  = kb * 32 + (l >> 4) * 8;
    const float* src = x + (size_t)row * IN_F + k0;
    unsigned w[4];
    #pragma unroll
    for (int e = 0; e < 4; ++e) {
        unsigned lo = __builtin_bit_cast(unsigned short, __float2bfloat16(src[2 * e]));
        unsigned hi = __builtin_bit_cast(unsigned short, __float2bfloat16(src[2 * e + 1]));
        w[e] = lo | (hi << 16);
    }
    i32x4 v = { (int)w[0], (int)w[1], (int)w[2], (int)w[3] };
    *reinterpret_cast<i32x4*>(frag + ((size_t)st * 8192 + kb * 64 + l) * 8) = v;
}

// ---------------------------------------------------------------------------
// Main: grid 688, 256 thr (4 waves). R13 geometry (best measured) with
// ASYNC DMA STAGING (global_load_lds, width=16) — the one untried mechanism.
// Block = 16 out-rows x full K=4096; wave w owns k [w*1024,+1024) as
// 8 units of 128 k, double-buffered (2 x 4KB raw-code bufs per wave).
//
// Staging a unit = 4 fire-and-forget DMA wave-instrs (1KB each, rows 4q..+3):
//   - LDS dest is LINEAR (HW: uniform base + lane*16) -> [row][granule] raw
//     int32 codes (granule = 4 int32 = 8 k, 16B).
//   - Bank swizzle applied on the GLOBAL SOURCE address (rule #21): lane's
//     source granule = gq ^ (row&7). XOR permutes 16B granules WITHIN the
//     row's contiguous 256B -> wave still covers one contiguous 1KB: zero
//     coalescing loss. LDS[row][gq] holds global granule gq^(row&7).
//   - Reader (lane col,g; k-step t) wants global granule t*4+g of row col:
//     ds_read_b128 at col*64 + ((t*4+g)^(col&7))*4 dwords. Banks: granule'
//     mod 8 spans all 8 quads, 8 lanes/quad = 2 lanes/bank -> FREE (m136).
//   - No compaction: tabu index = raw dword & 255 (byte extract folds into
//     address math). No staging VGPRs, no ds_writes, no vmcnt->ds_write link.
// Sync per unit boundary: s_waitcnt vmcnt(0) + sched_barrier(0) (the memory
// clobber also stops cross-unit ds_read CSE — DMA writes are compiler-
// invisible). stage(u+1) issues right AFTER the wait -> flies under
// compute(u). Still ZERO block barriers in the K-loop; one final reduce
// barrier (R13 epilogue, red aliases wave's own dead buffers).
// ---------------------------------------------------------------------------
__global__ __launch_bounds__(256, 4) void nf4_gemm_kernel(
        const int* __restrict__ packed,
        const float* __restrict__ scales,
        const float* __restrict__ bias,
        const unsigned short* __restrict__ frag,
        float* __restrict__ out)
{
    __shared__ unsigned lds[9216];   // 1024 tabu (4x256) | 4 waves x 2048 dw

    const int tid  = threadIdx.x;
    const int wave = tid >> 6;
    const int lane = tid & 63;
    const int col  = lane & 15;
    const int g    = lane >> 4;

    const int n0 = blockIdx.x * NTILE;

    // ---- wave-private tabu (in-wave DS ordering; no barrier) ----
    #pragma unroll
    for (int q = 0; q < 4; ++q) {
        int e = q * 64 + lane;
        unsigned lo = __builtin_bit_cast(unsigned short, __float2bfloat16(NF4_LEVELS[e & 15]));
        unsigned hi = __builtin_bit_cast(unsigned short, __float2bfloat16(NF4_LEVELS[(e >> 4) & 15]));
        lds[wave * 256 + e] = lo | (hi << 16);
    }

    // ---- scales in registers: row n0+col, groups wave*8 .. +8 ----
    float scw[8];
    {
        const float* sp = scales + (size_t)(n0 + col) * 32 + wave * 8;
        float4v sv0 = *reinterpret_cast<const float4v*>(sp);
        float4v sv1 = *reinterpret_cast<const float4v*>(sp + 4);
        scw[0]=sv0.x; scw[1]=sv0.y; scw[2]=sv0.z; scw[3]=sv0.w;
        scw[4]=sv1.x; scw[5]=sv1.y; scw[6]=sv1.z; scw[7]=sv1.w;
    }

    unsigned* cbase = &lds[1024 + wave * 2048];   // this wave's 2 x 1024 dw

    // DMA-stage unit u (128 k x 16 rows = 4KB) into buf (u&1).
    // instr q covers rows 4q..4q+3; lane: rl = 4q+(lane>>4), gq = lane&15;
    // source granule = gq ^ (rl&7)  (16B-granule XOR, coalescing-preserving)
    #define STAGE(u)                                                           \
        _Pragma("unroll")                                                      \
        for (int q = 0; q < 4; ++q) {                                          \
            int rl = q * 4 + (lane >> 4);                                      \
            int gq = lane & 15;                                                \
            const int* srcp = packed                                           \
                + (size_t)(n0 + rl) * (IN_F / 2)                               \
                + wave * 512 + (u) * 64 + (gq ^ (rl & 7)) * 4;                 \
            __builtin_amdgcn_global_load_lds(                                  \
                (const __attribute__((address_space(1))) unsigned int*)srcp,   \
                (__attribute__((address_space(3))) unsigned int*)              \
                    (cbase + ((u) & 1) * 1024 + q * 256),                      \
                16, 0, 0);                                                     \
        }

    f32x4 acc0 = (f32x4){0.f,0.f,0.f,0.f};   // batch 0-15
    f32x4 acc1 = (f32x4){0.f,0.f,0.f,0.f};   // batch 16-31

    const unsigned short* f0 = frag;
    const unsigned short* f1 = frag + 65536;

    STAGE(0)

    #pragma unroll
    for (int u = 0; u < 8; ++u) {
        // boundary: drain stage(u) (and any spent A-loads); block ds hoisting
        asm volatile("s_waitcnt vmcnt(0)" ::: "memory");
        __builtin_amdgcn_sched_barrier(0);
        if (u + 1 < 8) { STAGE(u + 1) }          // flies under compute(u)

        // A fragments for this unit (8 x 1KB contiguous, L2-resident)
        bf16x8 A0[4], A1[4];
        #pragma unroll
        for (int t = 0; t < 4; ++t) {
            int kb = wave * 32 + u * 4 + t;
            A0[t] = *reinterpret_cast<const bf16x8*>(f0 + ((size_t)kb * 64 + lane) * 8);
            A1[t] = *reinterpret_cast<const bf16x8*>(f1 + ((size_t)kb * 64 + lane) * 8);
        }

        f32x4 t0 = (f32x4){0.f,0.f,0.f,0.f};
        f32x4 t1 = (f32x4){0.f,0.f,0.f,0.f};
        #pragma unroll
        for (int t = 0; t < 4; ++t) {
            // raw codes: b128 at swizzled granule (2 lanes/bank, free)
            i32x4 cd = *reinterpret_cast<const i32x4*>(
                &cbase[(u & 1) * 1024 + col * 64 + (((t * 4 + g) ^ (col & 7)) * 4)]);
            i32x4 bu;                            // bfrag once, both halves
            bu[0] = (int)lds[wave * 256 + ((unsigned)cd[0] & 255u)];
            bu[1] = (int)lds[wave * 256 + ((unsigned)cd[1] & 255u)];
            bu[2] = (int)lds[wave * 256 + ((unsigned)cd[2] & 255u)];
            bu[3] = (int)lds[wave * 256 + ((unsigned)cd[3] & 255u)];
            bf16x8 bf = __builtin_bit_cast(bf16x8, bu);
            t0 = __builtin_amdgcn_mfma_f32_16x16x32_bf16(A0[t], bf, t0, 0, 0, 0);
            t1 = __builtin_amdgcn_mfma_f32_16x16x32_bf16(A1[t], bf, t1, 0, 0, 0);
        }
        const float sc = scw[u];                 // unit == one scale group
        #pragma unroll
        for (int j = 0; j < 4; ++j) {
            acc0[j] = fmaf(sc, t0[j], acc0[j]);
            acc1[j] = fmaf(sc, t1[j], acc1[j]);
        }
    }

    // ---- epilogue: red aliases wave's own buffers (reads done, no DMA
    // outstanding: stage(7) drained at u=7 boundary) ----
    float* red = (float*)cbase;
    #pragma unroll
    for (int j = 0; j < 4; ++j) {
        red[(0 * 4 + j) * 64 + g * 16 + col] = acc0[j];
        red[(1 * 4 + j) * 64 + g * 16 + col] = acc1[j];
    }
    __syncthreads();             // the ONE barrier

    #pragma unroll
    for (int p = 0; p < 2; ++p) {
        int idx = p * 256 + tid;             // [0,512)
        int b   = idx >> 4;                  // batch row
        int c   = idx & 15;                  // out-feature local
        int h   = b >> 4;
        int r   = b & 15;
        int j   = r & 3;
        int g2  = r >> 2;
        int slot = (h * 4 + j) * 64 + g2 * 16 + c;
        const float* rbase = (const float*)&lds[1024];
        float s = rbase[slot] + rbase[2048 + slot]
                + rbase[4096 + slot] + rbase[6144 + slot];
        out[(size_t)b * OUT_F + n0 + c] = s + bias[n0 + c];
    }
}

// ---------------------------------------------------------------------------
extern "C" void kernel_launch(void* const* d_in, const int* in_sizes, int n_in,
                              void* d_out, int out_size, void* d_ws, size_t ws_size,
                              hipStream_t stream) {
    const float* x      = (const float*)d_in[0];
    const int*   packed = (const int*)d_in[1];
    const float* scales = (const float*)d_in[2];
    const float* bias   = (const float*)d_in[3];
    float* out = (float*)d_out;

    unsigned short* frag = (unsigned short*)d_ws;   // 256 KB

    prelude_kernel<<<64, 256, 0, stream>>>(x, frag);
    nf4_gemm_kernel<<<GRID_N, 256, 0, stream>>>(packed, scales, bias, frag, out);
}